// Round 6
// baseline (50.429 us; speedup 1.0000x reference)
//
#include <hip/hip_runtime.h>

#define NB 8
#define SS 2048
#define DD 128
// 1/sqrt(8) * log2(e): exp(x/sqrt8) = exp2(x*SCALE2)
#define SCALE2 0.5101817664764817f
#define NEGINF -3.0e38f

typedef _Float16 f16x8 __attribute__((ext_vector_type(8)));
typedef float f32x4 __attribute__((ext_vector_type(4)));
typedef unsigned short u16;
typedef u16 u16x8 __attribute__((ext_vector_type(8)));
typedef unsigned int u32;

__device__ __forceinline__ u32 pkrtz(float a, float b) {
    u32 w;
    asm("v_cvt_pkrtz_f16_f32 %0, %1, %2" : "=v"(w) : "v"(a), "v"(b));
    return w;
}

// ---------------- Kernel 1: U = quantum_measure(x, theta) ----------------
// Fragment-order layouts for mfma_f32_16x16x32_f16:
//  G1': per 16-row tile t16, chunk16B[t16*256 + w4*64 + l] = U[t16*16 + (l&15)][w4*32 + (l>>4)*8 + 0..7]
//       (serves K A-frags AND Q B-frags: addr = t16*4096B + w4*1024B + l*16B)
//  G2': per 32-row tile t32, chunk16B[t32*512 + dt*64 + l] = U[t32*32 + (l>>4)*8 + 0..7][dt*16 + (l&15)]
//       (serves V B-frags: addr = t32*8192B + dt*1024B + l*16B)
__global__ __launch_bounds__(512) void qmeasure_kernel(const float* __restrict__ x,
                                                       const float* __restrict__ theta,
                                                       u16* __restrict__ G1,
                                                       u16* __restrict__ G2) {
    __shared__ u16 olds[32][136];
    const int bid = blockIdx.x;
    const int b = bid & 7;
    const int t = bid >> 3;          // 32-row tile 0..63
    const int tid = threadIdx.x;
    const int s = tid >> 4;
    const int c = tid & 15;

    float th[8];
    *(float4*)th = *(const float4*)theta;
    *(float4*)(th + 4) = *(const float4*)(theta + 4);

    const float* xp = x + (((size_t)b * SS + t * 32 + s) * DD) + c * 8;
    float4 a = *(const float4*)xp;
    float4 a2 = *(const float4*)(xp + 4);
    float cc[8];
    cc[0] = __cosf(a.x + th[0]);  cc[1] = __cosf(a.y + th[1]);
    cc[2] = __cosf(a.z + th[2]);  cc[3] = __cosf(a.w + th[3]);
    cc[4] = __cosf(a2.x + th[4]); cc[5] = __cosf(a2.y + th[5]);
    cc[6] = __cosf(a2.z + th[6]); cc[7] = __cosf(a2.w + th[7]);
    float o[8];
    o[1] = cc[0] * cc[1];
    o[2] = o[1] * cc[2]; o[3] = o[2] * cc[3]; o[4] = o[3] * cc[4];
    o[5] = o[4] * cc[5]; o[6] = o[5] * cc[6]; o[7] = o[6] * cc[7];
    float z = cc[1] * cc[2]; z *= cc[3]; z *= cc[4]; z *= cc[5]; z *= cc[6]; z *= cc[7];
    o[0] = z;

    u16x8 w;
#pragma unroll
    for (int e = 0; e < 8; ++e) w[e] = __builtin_bit_cast(u16, (_Float16)o[e]);
    *(u16x8*)&olds[s][c * 8] = w;
    __syncthreads();

    // G1' store: tid -> sub(1b), w4(2b), l(6b); coalesced 16B/thread
    {
        const int sub = tid >> 8, w4 = (tid >> 6) & 3, l = tid & 63;
        u16x8 g = *(const u16x8*)&olds[sub * 16 + (l & 15)][w4 * 32 + ((l >> 4) & 3) * 8];
        const int chunk = (2 * t + sub) * 256 + w4 * 64 + l;
        *(u16x8*)(G1 + (size_t)b * (SS * DD) + (size_t)chunk * 8) = g;
    }
    // G2' store: tid -> dt(3b), l(6b)
    {
        const int dt = tid >> 6, l = tid & 63;
        u16x8 g;
#pragma unroll
        for (int e = 0; e < 8; ++e) g[e] = olds[((l >> 4) & 3) * 8 + e][dt * 16 + (l & 15)];
        const int chunk = t * 512 + dt * 64 + l;
        *(u16x8*)(G2 + (size_t)b * (SS * DD) + (size_t)chunk * 8) = g;
    }
}

// ---------------- Kernel 2: flash attention, 16x16 tiles, 4 waves/SIMD ----------------
// grid 256 = 8 batches (bid&7, XCD-pinned) x 32 q-groups of 64 rows.
// block 1024 thr = 16 waves = 4 qt (16-row q-tile) x 4 kq (512-kv quarter).
// Per wave: S^T = K.Q^T (16x16x32, C col=q=lane&15, row=kv); in-register online softmax
// (reduce via shfl_xor 16/32); P redistributed to A-frag via 8 bpermute; O = P.V
// (C row=q=(l>>4)*4+r, col=d). No LDS in main loop; raw s_barrier/iter keeps the 4
// same-kq waves L1-aligned. 4-way kq merge via LDS at the end.
__global__ __launch_bounds__(1024, 4) void qattn_kernel(const u16* __restrict__ G1g,
                                                        const u16* __restrict__ G2g,
                                                        float* __restrict__ out) {
    __shared__ float obuf[4][3][4][4][64];   // [qt][kq-1][j][r][lane] = 48 KB
    __shared__ float mlb[4][4][2][16];       // [qt][kq][m/l][q] = 2 KB

    const int tid = threadIdx.x;
    const int ln = tid & 63;
    const int wv = tid >> 6;       // 0..15
    const int qt = wv & 3;
    const int kq = wv >> 2;        // kv quarter
    const int h = ln >> 4;         // 0..3
    const int q16 = ln & 15;
    const int bid = blockIdx.x;
    const int b = bid & 7;
    const int qg = bid >> 3;       // 0..31

    const u16* Gb1 = G1g + (size_t)b * (SS * DD);
    const u16* Gb2 = G2g + (size_t)b * (SS * DD);

    // Q B-frags (same layout as K A-frags)
    const int qtile = qg * 4 + qt;             // 16-row q tile 0..127
    f16x8 qf[4];
#pragma unroll
    for (int w4 = 0; w4 < 4; ++w4)
        qf[w4] = *(const f16x8*)(Gb1 + (size_t)qtile * 2048 + w4 * 512 + ln * 8);

    f32x4 accO[8];
#pragma unroll
    for (int dt = 0; dt < 8; ++dt)
#pragma unroll
        for (int r = 0; r < 4; ++r) accO[dt][r] = 0.f;
    float m = NEGINF, lsum = 0.f;

    const int L0 = ((h & 1) << 5) + q16;   // bpermute src lanes for P redistribution
    const int L1 = L0 + 16;
    const bool hlo = (h < 2);

    for (int it = 0; it < 16; ++it) {
        // K A-frags: two 16-row tiles (32 kv)
        const int t16 = kq * 32 + it * 2;
        f16x8 kf0[4], kf1[4];
        {
            const u16* kp = Gb1 + (size_t)t16 * 2048 + ln * 8;
#pragma unroll
            for (int w4 = 0; w4 < 4; ++w4) kf0[w4] = *(const f16x8*)(kp + w4 * 512);
#pragma unroll
            for (int w4 = 0; w4 < 4; ++w4) kf1[w4] = *(const f16x8*)(kp + 2048 + w4 * 512);
        }
        f32x4 a0, a1;
#pragma unroll
        for (int r = 0; r < 4; ++r) { a0[r] = 0.f; a1[r] = 0.f; }
        __builtin_amdgcn_s_setprio(1);
#pragma unroll
        for (int w4 = 0; w4 < 4; ++w4)
            a0 = __builtin_amdgcn_mfma_f32_16x16x32_f16(kf0[w4], qf[w4], a0, 0, 0, 0);
#pragma unroll
        for (int w4 = 0; w4 < 4; ++w4)
            a1 = __builtin_amdgcn_mfma_f32_16x16x32_f16(kf1[w4], qf[w4], a1, 0, 0, 0);
        __builtin_amdgcn_s_setprio(0);

        // V B-frags: issue now, consumed after softmax
        f16x8 vf[8];
        {
            const u16* vp = Gb2 + (size_t)(kq * 16 + it) * 4096 + ln * 8;
#pragma unroll
            for (int dt = 0; dt < 8; ++dt) vf[dt] = *(const f16x8*)(vp + dt * 512);
        }

        // online softmax; lane owns q=q16, kv {4h..4h+3, 16+4h..16+4h+3}
        float tmax = fmaxf(fmaxf(fmaxf(a0[0], a0[1]), fmaxf(a0[2], a0[3])),
                           fmaxf(fmaxf(a1[0], a1[1]), fmaxf(a1[2], a1[3]))) * SCALE2;
        tmax = fmaxf(tmax, __shfl_xor(tmax, 16));
        tmax = fmaxf(tmax, __shfl_xor(tmax, 32));
        if (!__all(tmax <= m + 8.f)) {       // defer-max: P bounded by 2^8
            const float mnew = fmaxf(m, tmax);
            const float corr = exp2f(m - mnew);
            lsum *= corr;
            // accO rows are q = 4h+r -> fetch corr per element from lane 4h+r
            float c0 = __shfl(corr, (h << 2) + 0);
            float c1 = __shfl(corr, (h << 2) + 1);
            float c2 = __shfl(corr, (h << 2) + 2);
            float c3 = __shfl(corr, (h << 2) + 3);
#pragma unroll
            for (int dt = 0; dt < 8; ++dt) {
                accO[dt][0] *= c0; accO[dt][1] *= c1;
                accO[dt][2] *= c2; accO[dt][3] *= c3;
            }
            m = mnew;
        }
#pragma unroll
        for (int r = 0; r < 4; ++r) {
            a0[r] = exp2f(a0[r] * SCALE2 - m);
            a1[r] = exp2f(a1[r] * SCALE2 - m);
        }
        float rs = ((a0[0] + a0[1]) + (a0[2] + a0[3])) + ((a1[0] + a1[1]) + (a1[2] + a1[3]));
        rs += __shfl_xor(rs, 16);
        rs += __shfl_xor(rs, 32);
        lsum += rs;

        // pack P to f16 words; redistribute to A-frag (lane needs P[q16][kv 8h..8h+7])
        u32 w0 = pkrtz(a0[0], a0[1]);        // kv 4h, 4h+1
        u32 w1 = pkrtz(a0[2], a0[3]);        // kv 4h+2, 4h+3
        u32 w2 = pkrtz(a1[0], a1[1]);        // kv 16+4h, +1
        u32 w3 = pkrtz(a1[2], a1[3]);        // kv 16+4h+2, +3
        u32 s00 = __shfl(w0, L0), s10 = __shfl(w1, L0);
        u32 s20 = __shfl(w2, L0), s30 = __shfl(w3, L0);
        u32 s01 = __shfl(w0, L1), s11 = __shfl(w1, L1);
        u32 s21 = __shfl(w2, L1), s31 = __shfl(w3, L1);
        union { u32 w[4]; f16x8 v; } pu;
        pu.w[0] = hlo ? s00 : s20;
        pu.w[1] = hlo ? s10 : s30;
        pu.w[2] = hlo ? s01 : s21;
        pu.w[3] = hlo ? s11 : s31;

        // O += P . V  (one MFMA per 16-d tile, K=32)
        __builtin_amdgcn_s_setprio(1);
#pragma unroll
        for (int dt = 0; dt < 8; ++dt)
            accO[dt] = __builtin_amdgcn_mfma_f32_16x16x32_f16(pu.v, vf[dt], accO[dt], 0, 0, 0);
        __builtin_amdgcn_s_setprio(0);

        __builtin_amdgcn_s_barrier();   // rate-limiter only (no memory drain): keeps L1 sharing
    }

    // ---- 4-way kq merge via LDS, two d-half rounds ----
    __syncthreads();
    if (ln < 16) {
        mlb[qt][kq][0][ln] = m;
        mlb[qt][kq][1][ln] = lsum;
    }
#pragma unroll
    for (int dh = 0; dh < 2; ++dh) {
        if (kq > 0) {
#pragma unroll
            for (int j = 0; j < 4; ++j)
#pragma unroll
                for (int r = 0; r < 4; ++r)
                    obuf[qt][kq - 1][j][r][ln] = accO[dh * 4 + j][r];
        }
        __syncthreads();
        if (kq == 0) {
            float wgt[4][4], linv[4];
#pragma unroll
            for (int r = 0; r < 4; ++r) {
                const int qq = h * 4 + r;
                float m0 = mlb[qt][0][0][qq], m1 = mlb[qt][1][0][qq];
                float m2 = mlb[qt][2][0][qq], m3 = mlb[qt][3][0][qq];
                float l0 = mlb[qt][0][1][qq], l1 = mlb[qt][1][1][qq];
                float l2 = mlb[qt][2][1][qq], l3 = mlb[qt][3][1][qq];
                const float ms = fmaxf(fmaxf(m0, m1), fmaxf(m2, m3));
                wgt[0][r] = exp2f(m0 - ms); wgt[1][r] = exp2f(m1 - ms);
                wgt[2][r] = exp2f(m2 - ms); wgt[3][r] = exp2f(m3 - ms);
                linv[r] = 1.f / (l0 * wgt[0][r] + l1 * wgt[1][r] +
                                 l2 * wgt[2][r] + l3 * wgt[3][r]);
            }
            float* ob = out + ((size_t)b * SS + qtile * 16) * DD;
#pragma unroll
            for (int j = 0; j < 4; ++j) {
                const int dt = dh * 4 + j;
#pragma unroll
                for (int r = 0; r < 4; ++r) {
                    const float o = accO[dt][r] * wgt[0][r] +
                                    obuf[qt][0][j][r][ln] * wgt[1][r] +
                                    obuf[qt][1][j][r][ln] * wgt[2][r] +
                                    obuf[qt][2][j][r][ln] * wgt[3][r];
                    ob[(size_t)(h * 4 + r) * DD + dt * 16 + q16] = o * linv[r];
                }
            }
        }
        __syncthreads();
    }
}

extern "C" void kernel_launch(void* const* d_in, const int* in_sizes, int n_in,
                              void* d_out, int out_size, void* d_ws, size_t ws_size,
                              hipStream_t stream) {
    const float* x = (const float*)d_in[0];
    const float* theta = (const float*)d_in[1];
    float* outp = (float*)d_out;
    u16* G1 = (u16*)d_ws;                       // 4 MB
    u16* G2 = G1 + (size_t)NB * SS * DD;        // +4 MB

    qmeasure_kernel<<<512, 512, 0, stream>>>(x, theta, G1, G2);
    qattn_kernel<<<256, 1024, 0, stream>>>(G1, G2, outp);
}

// Round 7
// 40.663 us; speedup vs baseline: 1.2402x; 1.2402x over previous
//
#include <hip/hip_runtime.h>

#define NB 8
#define SS 2048
#define DD 128
// 1/sqrt(8) * log2(e): exp(x/sqrt8) = exp2(x*SCALE2)
#define SCALE2 0.5101817664764817f
#define NEGINF -3.0e38f

typedef _Float16 f16x8 __attribute__((ext_vector_type(8)));
typedef float f32x16 __attribute__((ext_vector_type(16)));
typedef unsigned short u16;
typedef u16 u16x8 __attribute__((ext_vector_type(8)));
typedef unsigned int u32;

__device__ __forceinline__ u32 pkrtz(float a, float b) {
    u32 w;
    asm("v_cvt_pkrtz_f16_f32 %0, %1, %2" : "=v"(w) : "v"(a), "v"(b));
    return w;
}

// async global->LDS, 16B/lane; LDS dest is wave-uniform base (HW adds lane*16)
__device__ __forceinline__ void gload_lds16(const u16* g, u16* l) {
    __builtin_amdgcn_global_load_lds(
        (const __attribute__((address_space(1))) unsigned*)g,
        (__attribute__((address_space(3))) unsigned*)l, 16, 0, 0);
}

// ---------------- Kernel 1: U = quantum_measure(x, theta) ----------------
// Fragment-order f16 layouts (per batch, per 32-row s-tile t), for 32x32x16 MFMA:
//  G1 : chunk16B[t*512 + kc*64 + hi*32 + r]  holds U[t*32+r][kc*16+hi*8 + 0..7]
//  G2t: chunk16B[t*512 + (dt*2+kc2)*64 + hi*32 + lo5] holds U[t*32+kc2*16+hi*8+u][dt*32+lo5]
// Both stores coalesced (1KB/wave) via the LDS tile.
__global__ __launch_bounds__(512) void qmeasure_kernel(const float* __restrict__ x,
                                                       const float* __restrict__ theta,
                                                       u16* __restrict__ G1,
                                                       u16* __restrict__ G2) {
    __shared__ u16 olds[32][136];
    const int bid = blockIdx.x;
    const int b = bid & 7;
    const int t = bid >> 3;
    const int tid = threadIdx.x;
    const int s = tid >> 4;
    const int c = tid & 15;

    float th[8];
    *(float4*)th = *(const float4*)theta;
    *(float4*)(th + 4) = *(const float4*)(theta + 4);

    const float* xp = x + (((size_t)b * SS + t * 32 + s) * DD) + c * 8;
    float4 a = *(const float4*)xp;
    float4 a2 = *(const float4*)(xp + 4);
    float cc[8];
    cc[0] = __cosf(a.x + th[0]);  cc[1] = __cosf(a.y + th[1]);
    cc[2] = __cosf(a.z + th[2]);  cc[3] = __cosf(a.w + th[3]);
    cc[4] = __cosf(a2.x + th[4]); cc[5] = __cosf(a2.y + th[5]);
    cc[6] = __cosf(a2.z + th[6]); cc[7] = __cosf(a2.w + th[7]);
    float o[8];
    o[1] = cc[0] * cc[1];
    o[2] = o[1] * cc[2]; o[3] = o[2] * cc[3]; o[4] = o[3] * cc[4];
    o[5] = o[4] * cc[5]; o[6] = o[5] * cc[6]; o[7] = o[6] * cc[7];
    float z = cc[1] * cc[2]; z *= cc[3]; z *= cc[4]; z *= cc[5]; z *= cc[6]; z *= cc[7];
    o[0] = z;

    u16x8 w;
#pragma unroll
    for (int e = 0; e < 8; ++e) w[e] = __builtin_bit_cast(u16, (_Float16)o[e]);
    *(u16x8*)&olds[s][c * 8] = w;
    __syncthreads();

    {
        const int kc = tid >> 6, hh = (tid >> 5) & 1, r = tid & 31;
        u16x8 g;
#pragma unroll
        for (int u = 0; u < 8; ++u) g[u] = olds[r][kc * 16 + hh * 8 + u];
        *(u16x8*)(G1 + (size_t)b * (SS * DD) + ((size_t)t * 512 + tid) * 8) = g;
    }
    {
        const int lo5 = tid & 31;
        const int hh = (tid >> 5) & 1;
        const int dkc = tid >> 6;
        const int dt = dkc >> 1, kc2 = dkc & 1;
        u16x8 g;
#pragma unroll
        for (int u = 0; u < 8; ++u) g[u] = olds[kc2 * 16 + hh * 8 + u][dt * 32 + lo5];
        const int chunk = t * 512 + dkc * 64 + hh * 32 + lo5;
        *(u16x8*)(G2 + (size_t)b * (SS * DD) + (size_t)chunk * 8) = g;
    }
}

// ---------------- Kernel 2: flash attention, LDS-staged, counted-vmcnt pipeline ------
// grid 256 = 8 batches (bid&7) x 32 q-groups of 64 rows. 512 thr = 8 waves = 2qw x 4kq.
// Each K/V byte enters the CU once (wave (qw,kq) stages its duty tile via global_load_lds;
// both qw waves consume it) -> L2 ingress 256 MB. Double-buffered; next tile's 8 loads
// stay in flight across both raw s_barriers (vmcnt(8), never 0 mid-loop).
__global__ __launch_bounds__(512, 2) void qattn_kernel(const u16* __restrict__ G1g,
                                                       const u16* __restrict__ G2g,
                                                       float* __restrict__ out) {
    __shared__ __align__(16) u16 sb[2][2][4][4096];   // [dbuf][K/V][kq][8KB tile] = 128 KB

    const int tid = threadIdx.x;
    const int lane = tid & 63;
    const int wave = tid >> 6;
    const int lo5 = lane & 31;
    const int hi = lane >> 5;
    const int qw = wave & 1;
    const int kq = wave >> 1;
    const int bid = blockIdx.x;
    const int b = bid & 7;
    const int qg = bid >> 3;

    const u16* G1b = G1g + (size_t)b * (SS * DD);
    const u16* G2b = G2g + (size_t)b * (SS * DD);
    const u16* sbase = (qw ? G2b : G1b);   // staging duty: qw0->K, qw1->V^T

    // Q fragments (B-operand), loaded once (8 outstanding VMEM)
    f16x8 qf[8];
    {
        const u16* qp = G1b + (size_t)(qg * 2 + qw) * 4096 + lane * 8;
#pragma unroll
        for (int kc = 0; kc < 8; ++kc) qf[kc] = *(const f16x8*)(qp + kc * 512);
    }

    // prologue stages: tile0 -> buf0, tile1 -> buf1 (8 gload_lds each)
#pragma unroll
    for (int pb = 0; pb < 2; ++pb) {
        const u16* src = sbase + (size_t)(kq * 16 + pb) * 4096 + lane * 8;
        u16* dst = &sb[pb][qw][kq][0];
#pragma unroll
        for (int w = 0; w < 8; ++w) gload_lds16(src + w * 512, dst + w * 512);
    }

    f32x16 accT[4];
#pragma unroll
    for (int dt = 0; dt < 4; ++dt)
#pragma unroll
        for (int e = 0; e < 16; ++e) accT[dt][e] = 0.f;
    float m = NEGINF, l = 0.f;

    for (int it = 0; it < 16; ++it) {
        const int cur = it & 1;
        // wait: all but the newest 8 VMEM ops done => tile `it` (and Q) landed;
        // tile it+1's 8 loads stay in flight across the barrier.
        if (it < 15) asm volatile("s_waitcnt vmcnt(8)" ::: "memory");
        else         asm volatile("s_waitcnt vmcnt(0)" ::: "memory");
        __builtin_amdgcn_sched_barrier(0);
        __builtin_amdgcn_s_barrier();          // tile `it` visible to all waves
        __builtin_amdgcn_sched_barrier(0);

        const u16* Kb = &sb[cur][0][kq][0] + lane * 8;
        const u16* Vb = &sb[cur][1][kq][0] + lane * 8;

        // K frags + QK^T as two independent 4-MFMA chains
        f32x16 acA, acB;
#pragma unroll
        for (int e = 0; e < 16; ++e) { acA[e] = 0.f; acB[e] = 0.f; }
        __builtin_amdgcn_s_setprio(1);
#pragma unroll
        for (int kc = 0; kc < 4; ++kc) {
            f16x8 kf = *(const f16x8*)(Kb + kc * 512);
            acA = __builtin_amdgcn_mfma_f32_32x32x16_f16(kf, qf[kc], acA, 0, 0, 0);
        }
#pragma unroll
        for (int kc = 4; kc < 8; ++kc) {
            f16x8 kf = *(const f16x8*)(Kb + kc * 512);
            acB = __builtin_amdgcn_mfma_f32_32x32x16_f16(kf, qf[kc], acB, 0, 0, 0);
        }
        __builtin_amdgcn_s_setprio(0);
        f32x16 acc = acA + acB;

        // V frags (LDS, issue before softmax; consumed by PV)
        f16x8 vf[8];
#pragma unroll
        for (int j = 0; j < 8; ++j) vf[j] = *(const f16x8*)(Vb + j * 512);

        // online softmax (exp2 domain), defer-max THR=8
        float ma = fmaxf(fmaxf(acc[0], acc[1]), acc[2]);
        float mb = fmaxf(fmaxf(acc[8], acc[9]), acc[10]);
        ma = fmaxf(fmaxf(ma, acc[3]), acc[4]);
        mb = fmaxf(fmaxf(mb, acc[11]), acc[12]);
        ma = fmaxf(fmaxf(ma, acc[5]), acc[6]);
        mb = fmaxf(fmaxf(mb, acc[13]), acc[14]);
        ma = fmaxf(fmaxf(ma, acc[7]), mb);
        float tmax = fmaxf(ma, acc[15]) * SCALE2;
        tmax = fmaxf(tmax, __shfl_xor(tmax, 32));
        if (!__all(tmax <= m + 8.f)) {
            const float mnew = fmaxf(m, tmax);
            const float corr = exp2f(m - mnew);
            l *= corr;
#pragma unroll
            for (int dt = 0; dt < 4; ++dt)
#pragma unroll
                for (int e = 0; e < 16; ++e) accT[dt][e] *= corr;
            m = mnew;
        }
#pragma unroll
        for (int r = 0; r < 16; ++r) acc[r] = exp2f(acc[r] * SCALE2 - m);
        float s0 = (acc[0] + acc[1]) + (acc[2] + acc[3]);
        float s1 = (acc[4] + acc[5]) + (acc[6] + acc[7]);
        float s2 = (acc[8] + acc[9]) + (acc[10] + acc[11]);
        float s3 = (acc[12] + acc[13]) + (acc[14] + acc[15]);
        float rowsum = (s0 + s1) + (s2 + s3);
        rowsum += __shfl_xor(rowsum, 32);
        l += rowsum;

        // P^T B-frags via cvt_pk + permlane32_swap
        f16x8 pa[2];
#pragma unroll
        for (int kc2 = 0; kc2 < 2; ++kc2) {
            const int r0 = kc2 * 8;
            u32 w0 = pkrtz(acc[r0 + 0], acc[r0 + 1]);
            u32 w2 = pkrtz(acc[r0 + 4], acc[r0 + 5]);
            asm("v_permlane32_swap_b32 %0, %1" : "+v"(w0), "+v"(w2));
            u32 w1 = pkrtz(acc[r0 + 2], acc[r0 + 3]);
            u32 w3 = pkrtz(acc[r0 + 6], acc[r0 + 7]);
            asm("v_permlane32_swap_b32 %0, %1" : "+v"(w1), "+v"(w3));
            union { u32 w[4]; f16x8 v; } u;
            u.w[0] = w0; u.w[1] = w1; u.w[2] = w2; u.w[3] = w3;
            pa[kc2] = u.v;
        }

        // O^T += V^T . P^T (4 independent 2-chains)
        __builtin_amdgcn_s_setprio(1);
#pragma unroll
        for (int dt = 0; dt < 4; ++dt) {
            f32x16 a = accT[dt];
            a = __builtin_amdgcn_mfma_f32_32x32x16_f16(vf[dt * 2 + 0], pa[0], a, 0, 0, 0);
            a = __builtin_amdgcn_mfma_f32_32x32x16_f16(vf[dt * 2 + 1], pa[1], a, 0, 0, 0);
            accT[dt] = a;
        }
        __builtin_amdgcn_s_setprio(0);

        // my LDS reads done; barrier => ALL waves done reading buf[cur]
        asm volatile("s_waitcnt lgkmcnt(0)" ::: "memory");
        __builtin_amdgcn_sched_barrier(0);
        __builtin_amdgcn_s_barrier();
        __builtin_amdgcn_sched_barrier(0);

        // now safe to overwrite buf[cur] with tile it+2 (stays in flight next iter)
        if (it < 14) {
            const u16* src = sbase + (size_t)(kq * 16 + it + 2) * 4096 + lane * 8;
            u16* dst = &sb[cur][qw][kq][0];
#pragma unroll
            for (int w = 0; w < 8; ++w) gload_lds16(src + w * 512, dst + w * 512);
        }
    }

    // ---- 4-way kq merge via LDS (alias dead staging buffers) ----
    __syncthreads();
    float* obuf = (float*)(&sb[0][0][0][0]);                           // [2][3][2][16][64] f32
    float* mlb = (float*)((unsigned char*)(&sb[0][0][0][0]) + 49152);  // [2][3][2][32] f32
    float* orow = out + ((size_t)b * SS + qg * 64 + qw * 32 + lo5) * DD;
#pragma unroll
    for (int half = 0; half < 2; ++half) {
        if (kq > 0) {
            if (half == 0 && hi == 0) {
                mlb[((qw * 3 + (kq - 1)) * 2 + 0) * 32 + lo5] = m;
                mlb[((qw * 3 + (kq - 1)) * 2 + 1) * 32 + lo5] = l;
            }
#pragma unroll
            for (int dh = 0; dh < 2; ++dh)
#pragma unroll
                for (int r = 0; r < 16; ++r)
                    obuf[(((qw * 3 + (kq - 1)) * 2 + dh) * 16 + r) * 64 + lane] =
                        accT[half * 2 + dh][r];
        }
        __syncthreads();
        if (kq == 0) {
            const float mj0 = mlb[((qw * 3 + 0) * 2 + 0) * 32 + lo5];
            const float lj0 = mlb[((qw * 3 + 0) * 2 + 1) * 32 + lo5];
            const float mj1 = mlb[((qw * 3 + 1) * 2 + 0) * 32 + lo5];
            const float lj1 = mlb[((qw * 3 + 1) * 2 + 1) * 32 + lo5];
            const float mj2 = mlb[((qw * 3 + 2) * 2 + 0) * 32 + lo5];
            const float lj2 = mlb[((qw * 3 + 2) * 2 + 1) * 32 + lo5];
            const float ms = fmaxf(fmaxf(m, mj0), fmaxf(mj1, mj2));
            const float w0 = exp2f(m - ms), w1 = exp2f(mj0 - ms);
            const float w2 = exp2f(mj1 - ms), w3 = exp2f(mj2 - ms);
            const float linv = 1.f / (l * w0 + lj0 * w1 + lj1 * w2 + lj2 * w3);
#pragma unroll
            for (int dh = 0; dh < 2; ++dh) {
                const int dt = half * 2 + dh;
#pragma unroll
                for (int r = 0; r < 16; ++r) {
                    const float o = accT[dt][r] * w0 +
                                    obuf[(((qw * 3 + 0) * 2 + dh) * 16 + r) * 64 + lane] * w1 +
                                    obuf[(((qw * 3 + 1) * 2 + dh) * 16 + r) * 64 + lane] * w2 +
                                    obuf[(((qw * 3 + 2) * 2 + dh) * 16 + r) * 64 + lane] * w3;
                    const int drow = (r & 3) + 8 * (r >> 2) + 4 * hi;
                    orow[dt * 32 + drow] = o * linv;
                }
            }
        }
        __syncthreads();
    }
}

extern "C" void kernel_launch(void* const* d_in, const int* in_sizes, int n_in,
                              void* d_out, int out_size, void* d_ws, size_t ws_size,
                              hipStream_t stream) {
    const float* x = (const float*)d_in[0];
    const float* theta = (const float*)d_in[1];
    float* outp = (float*)d_out;
    u16* G1 = (u16*)d_ws;                       // 4 MB
    u16* G2 = G1 + (size_t)NB * SS * DD;        // +4 MB

    qmeasure_kernel<<<512, 512, 0, stream>>>(x, theta, G1, G2);
    qattn_kernel<<<256, 512, 0, stream>>>(G1, G2, outp);
}